// Round 1
// baseline (3355.393 us; speedup 1.0000x reference)
//
#include <hip/hip_runtime.h>

constexpr int H = 1024, W = 1024, FID = 100, NF = 8;
constexpr int NPTS = 1 << 20, KSTEPS = 20;

__global__ __launch_bounds__(256)
void flame_kernel(const float* __restrict__ points,
                  const int* __restrict__ choices,
                  const float* __restrict__ A,
                  const float* __restrict__ b,
                  const float* __restrict__ fc,
                  const float* __restrict__ palette,
                  const float* __restrict__ min_vec,
                  const float* __restrict__ range_vec,
                  const int* __restrict__ skipp,
                  float* __restrict__ out)
{
    __shared__ float sA[NF * 4];
    __shared__ float sB[NF * 2];
    __shared__ float sFC[NF];
    __shared__ float4 sPal[FID + 1];

    const int t = threadIdx.x;
    if (t < NF * 4) sA[t] = A[t];
    if (t < NF * 2) sB[t] = b[t];
    if (t < NF)     sFC[t] = fc[t];
    for (int i = t; i < (FID + 1) * 4; i += 256) ((float*)sPal)[i] = palette[i];
    __syncthreads();

    const int n = blockIdx.x * 256 + t;
    float x = points[3 * n + 0];
    float y = points[3 * n + 1];
    float c = points[3 * n + 2];
    const float mx = min_vec[0], my = min_vec[1];
    const float rx = range_vec[0], ry = range_vec[1];
    const int skip = skipp[0];

    for (int k = 0; k < KSTEPS; ++k) {
        const int idx = choices[k * NPTS + n];
        const float a00 = sA[idx * 4 + 0], a01 = sA[idx * 4 + 1];
        const float a10 = sA[idx * 4 + 2], a11 = sA[idx * 4 + 3];
        const float nx = a00 * x + a01 * y + sB[idx * 2 + 0];
        const float ny = a10 * x + a11 * y + sB[idx * 2 + 1];
        c = 0.5f * (c + sFC[idx]);
        x = nx; y = ny;

        // palette interpolation (c in [0,1] -> _c in [0,100])
        const float _c = c * (float)FID;
        const float cf = floorf(_c);
        const float tt = _c - cf;
        const int cfi = (int)fminf(fmaxf(cf, 0.0f), (float)FID);
        const int cci = (int)fminf(fmaxf(ceilf(_c), 0.0f), (float)FID);
        const float4 pc = sPal[cci];
        const float4 pf = sPal[cfi];

        // astype(int32) truncates toward zero -> plain (int) cast matches.
        const int xb = (int)((nx - mx) * rx);
        const int yb = (int)((ny - my) * ry);

        // unsigned trick: (unsigned)xb < W  <=>  xb>=0 && xb<W (handles saturated casts)
        if (k >= skip && ((unsigned)xb < (unsigned)W) && ((unsigned)yb < (unsigned)H)) {
            const int p = xb * W + yb;   // img[:, xb, yb] : xb indexes dim of size H(==W)
            atomicAdd(out + p + 0 * H * W, tt * pc.x + (1.0f - tt) * pf.x);
            atomicAdd(out + p + 1 * H * W, tt * pc.y + (1.0f - tt) * pf.y);
            atomicAdd(out + p + 2 * H * W, tt * pc.z + (1.0f - tt) * pf.z);
            atomicAdd(out + p + 3 * H * W, tt * pc.w + (1.0f - tt) * pf.w);
        }
    }
}

extern "C" void kernel_launch(void* const* d_in, const int* in_sizes, int n_in,
                              void* d_out, int out_size, void* d_ws, size_t ws_size,
                              hipStream_t stream) {
    const float* points    = (const float*)d_in[0];
    const int*   choices   = (const int*)d_in[1];
    const float* A         = (const float*)d_in[2];
    const float* b         = (const float*)d_in[3];
    const float* fc        = (const float*)d_in[4];
    const float* palette   = (const float*)d_in[5];
    const float* min_vec   = (const float*)d_in[6];
    const float* range_vec = (const float*)d_in[7];
    const float* raw0      = (const float*)d_in[8];
    const int*   skipp     = (const int*)d_in[9];
    float* out = (float*)d_out;

    // Initialize output image from raw_image0 (reference accumulates into it).
    hipMemcpyAsync(out, raw0, (size_t)4 * H * W * sizeof(float),
                   hipMemcpyDeviceToDevice, stream);

    flame_kernel<<<NPTS / 256, 256, 0, stream>>>(
        points, choices, A, b, fc, palette, min_vec, range_vec, skipp, out);
}